// Round 1
// baseline (1003.210 us; speedup 1.0000x reference)
//
#include <hip/hip_runtime.h>

#define D_MODEL 512
#define D_FF    2048
#define NEXP    8
#define TOKENS  8192
#define MTILE   32
#define FCHUNK  256

typedef __bf16 bf16_t;
typedef __attribute__((ext_vector_type(8))) __bf16 bf16x8_t;
typedef __attribute__((ext_vector_type(4))) __bf16 bf16x4_t;
typedef __attribute__((ext_vector_type(4))) float  f32x4_t;

// ---- workspace layout (bytes) ----
#define XB_OFF     0u           // bf16 [8192][512]
#define W1T_OFF    8388608u     // bf16 [8][2048][512]  (w1t[e][f][d])
#define W2T_OFF    25165824u    // bf16 [8][512][2048]  (w2t[e][d][f])
#define UW1T_OFF   41943040u    // bf16 [2048][512]
#define UW2T_OFF   44040192u    // bf16 [512][2048]
#define S0_OFF     46137344u    // bf16 [8192][512]  top-1 contributions
#define S1_OFF     54525952u    // bf16 [8192][512]  top-2 contributions
#define CNT_OFF    62914560u    // int[16]
#define TOKL_OFF   62914624u    // int  [8][8192]   entry = (token<<1)|slot
#define GATEL_OFF  63176768u    // float[8][8192]
#define OMEGA_OFF  63438912u    // float[8192]
#define TLOG_OFF   63471680u    // double[8][8]

__device__ inline f32x4_t mfma_bf16(bf16x8_t a, bf16x8_t b, f32x4_t c) {
  return __builtin_amdgcn_mfma_f32_16x16x32_bf16(a, b, c, 0, 0, 0);
}

__global__ void k_convert_x(const float4* __restrict__ x, bf16x4_t* __restrict__ o, int n4) {
  int i = blockIdx.x * blockDim.x + threadIdx.x;
  if (i >= n4) return;
  float4 v = x[i];
  bf16x4_t r;
  r[0] = (bf16_t)v.x; r[1] = (bf16_t)v.y; r[2] = (bf16_t)v.z; r[3] = (bf16_t)v.w;
  o[i] = r;
}

// out[c*R + r] = bf16(in[r*C + c]); R,C multiples of 64; blockIdx.z = matrix index
__global__ void k_transpose(const float* __restrict__ in, bf16_t* __restrict__ out, int R, int C) {
  __shared__ float tile[64][65];
  const size_t mat = (size_t)blockIdx.z * R * C;
  in  += mat;
  out += mat;
  int r0 = blockIdx.y * 64, c0 = blockIdx.x * 64;
  for (int i = threadIdx.x; i < 64 * 64; i += 256) {
    int r = i >> 6, c = i & 63;
    tile[r][c] = in[(size_t)(r0 + r) * C + c0 + c];
  }
  __syncthreads();
  for (int i = threadIdx.x; i < 64 * 64; i += 256) {
    int rr = i >> 6, cc = i & 63;
    out[(size_t)(c0 + rr) * R + r0 + cc] = (bf16_t)tile[cc][rr];
  }
}

// t_logits[b][e] = task_embed[task_ids[b]] . gate_w[512:,e] + gate_b[e]  (f64)
__global__ void k_tlog(const int* __restrict__ task_ids, const float* __restrict__ task_emb,
                       const float* __restrict__ gate_w, const float* __restrict__ gate_b,
                       double* __restrict__ tlog) {
  int i = threadIdx.x;          // 64 threads: b = i>>3, e = i&7
  if (i >= 64) return;
  int b = i >> 3, e = i & 7;
  const float* te = task_emb + (size_t)task_ids[b] * D_MODEL;
  double acc = (double)gate_b[e];
  for (int d = 0; d < D_MODEL; d++)
    acc += (double)te[d] * (double)gate_w[(size_t)(D_MODEL + d) * NEXP + e];
  tlog[i] = acc;
}

// one wave per token: f64 logits, top-2 softmax, routing lists
__global__ void k_gate(const float* __restrict__ x, const float* __restrict__ gate_w,
                       const double* __restrict__ tlog,
                       float* __restrict__ logits_out,
                       int* __restrict__ counts, int* __restrict__ tokl,
                       float* __restrict__ gatel, float* __restrict__ omega) {
  int gtid = blockIdx.x * blockDim.x + threadIdx.x;
  int t = gtid >> 6;
  int lane = gtid & 63;
  if (t >= TOKENS) return;
  const float* xr = x + (size_t)t * D_MODEL;
  int d0 = lane * 8;
  float4 xa = *(const float4*)(xr + d0);
  float4 xc = *(const float4*)(xr + d0 + 4);
  float xv[8] = {xa.x, xa.y, xa.z, xa.w, xc.x, xc.y, xc.z, xc.w};
  double acc[NEXP];
#pragma unroll
  for (int e = 0; e < NEXP; e++) acc[e] = 0.0;
#pragma unroll
  for (int j = 0; j < 8; j++) {
    const float* gwr = gate_w + (size_t)(d0 + j) * NEXP;
    float4 g0 = *(const float4*)gwr;
    float4 g1 = *(const float4*)(gwr + 4);
    double xd = (double)xv[j];
    acc[0] += xd * (double)g0.x; acc[1] += xd * (double)g0.y;
    acc[2] += xd * (double)g0.z; acc[3] += xd * (double)g0.w;
    acc[4] += xd * (double)g1.x; acc[5] += xd * (double)g1.y;
    acc[6] += xd * (double)g1.z; acc[7] += xd * (double)g1.w;
  }
#pragma unroll
  for (int off = 32; off > 0; off >>= 1) {
#pragma unroll
    for (int e = 0; e < NEXP; e++) acc[e] += __shfl_xor(acc[e], off);
  }
  if (lane == 0) {
    int b = t >> 10;   // token -> batch (N=1024)
    double lg[NEXP];
#pragma unroll
    for (int e = 0; e < NEXP; e++) {
      lg[e] = acc[e] + tlog[b * NEXP + e];
      logits_out[(size_t)t * NEXP + e] = (float)lg[e];
    }
    int e0 = 0;
    for (int e = 1; e < NEXP; e++) if (lg[e] > lg[e0]) e0 = e;    // strict > : first idx wins ties (jax top_k)
    int e1 = (e0 == 0) ? 1 : 0;
    for (int e = 0; e < NEXP; e++) if (e != e0 && lg[e] > lg[e1]) e1 = e;
    double p0 = 1.0 / (1.0 + exp(lg[e1] - lg[e0]));
    float g0f = (float)p0;
    float g1f = (float)(1.0 - p0);
    omega[t] = 1.0f - g0f;                       // p0 >= 0.5 is the max gate
    int i0 = atomicAdd(counts + e0, 1);
    tokl[e0 * TOKENS + i0]  = (t << 1);
    gatel[e0 * TOKENS + i0] = g0f;
    int i1 = atomicAdd(counts + e1, 1);
    tokl[e1 * TOKENS + i1]  = (t << 1) | 1;
    gatel[e1 * TOKENS + i1] = g1f;
  }
}

// fused expert FFN: blockIdx.y = expert (8 = universal), 32 gathered tokens/block
__global__ __launch_bounds__(256) void k_ffn(
    const bf16_t* __restrict__ xb,
    const bf16_t* __restrict__ w1t, const bf16_t* __restrict__ w2t,
    const bf16_t* __restrict__ uw1t, const bf16_t* __restrict__ uw2t,
    const float* __restrict__ b1, const float* __restrict__ b2,
    const float* __restrict__ ub1, const float* __restrict__ ub2,
    const int* __restrict__ counts, const int* __restrict__ tokl,
    const float* __restrict__ gatel, const float* __restrict__ omega,
    bf16_t* __restrict__ s0, bf16_t* __restrict__ s1,
    float* __restrict__ out) {
  const int e = blockIdx.y;
  const bool uni = (e == NEXP);
  const int count = uni ? TOKENS : counts[e];
  const int base = blockIdx.x * MTILE;
  if (base >= count) return;

  const bf16_t* W1 = uni ? uw1t : (w1t + (size_t)e * D_FF * D_MODEL);   // [F][D]
  const bf16_t* W2 = uni ? uw2t : (w2t + (size_t)e * D_MODEL * D_FF);   // [D][F]
  const float*  B1 = uni ? ub1 : (b1 + e * D_FF);
  const float*  B2 = uni ? ub2 : (b2 + e * D_MODEL);

  __shared__ bf16_t hs[MTILE][FCHUNK + 8];   // +8 pad: 16B-aligned rows, 2-way banks
  __shared__ int   rtok[MTILE];
  __shared__ float rgate[MTILE];
  __shared__ int   rslot[MTILE];

  const int tid = threadIdx.x;
  if (tid < MTILE) {
    int idx = base + tid;
    int tk = 0, sl = 3; float g = 0.f;
    if (idx < count) {
      if (uni) { tk = idx; sl = 2; g = omega[idx]; }
      else {
        int en = tokl[e * TOKENS + idx];
        tk = en >> 1; sl = en & 1; g = gatel[e * TOKENS + idx];
      }
    }
    rtok[tid] = tk; rgate[tid] = g; rslot[tid] = sl;
  }
  __syncthreads();

  const int wave = tid >> 6;
  const int lane = tid & 63;
  const int l16  = lane & 15;
  const int quad = lane >> 4;

  const bf16_t* arow0 = xb + (size_t)rtok[l16]      * D_MODEL + quad * 8;
  const bf16_t* arow1 = xb + (size_t)rtok[l16 + 16] * D_MODEL + quad * 8;

  f32x4_t yacc[2][8];
#pragma unroll
  for (int mt = 0; mt < 2; mt++)
#pragma unroll
    for (int nt = 0; nt < 8; nt++) yacc[mt][nt] = f32x4_t{0.f, 0.f, 0.f, 0.f};

  for (int f0 = 0; f0 < D_FF; f0 += FCHUNK) {
    // ---- GEMM1: h[32][FCHUNK] = x @ W1   (wave owns 64 f-cols) ----
    f32x4_t hacc[2][4];
#pragma unroll
    for (int mt = 0; mt < 2; mt++)
#pragma unroll
      for (int nt = 0; nt < 4; nt++) hacc[mt][nt] = f32x4_t{0.f, 0.f, 0.f, 0.f};

    const bf16_t* w1p = W1 + (size_t)(f0 + wave * 64 + l16) * D_MODEL + quad * 8;
#pragma unroll 4
    for (int k0 = 0; k0 < D_MODEL; k0 += 32) {
      bf16x8_t a0 = *(const bf16x8_t*)(arow0 + k0);
      bf16x8_t a1 = *(const bf16x8_t*)(arow1 + k0);
#pragma unroll
      for (int nt = 0; nt < 4; nt++) {
        bf16x8_t bb = *(const bf16x8_t*)(w1p + (size_t)nt * 16 * D_MODEL + k0);
        hacc[0][nt] = mfma_bf16(a0, bb, hacc[0][nt]);
        hacc[1][nt] = mfma_bf16(a1, bb, hacc[1][nt]);
      }
    }

    __syncthreads();   // previous chunk's GEMM2 reads of hs complete
    // gelu(exact) + bias -> LDS (bf16)
#pragma unroll
    for (int nt = 0; nt < 4; nt++) {
      int fl = wave * 64 + nt * 16 + l16;
      float bias = B1[f0 + fl];
#pragma unroll
      for (int mt = 0; mt < 2; mt++) {
#pragma unroll
        for (int i = 0; i < 4; i++) {
          int row = mt * 16 + quad * 4 + i;
          float h = hacc[mt][nt][i] + bias;
          float gv = 0.5f * h * (1.0f + erff(h * 0.70710678118654752f));
          hs[row][fl] = (bf16_t)gv;
        }
      }
    }
    __syncthreads();

    // ---- GEMM2: y[32][512] += h_chunk @ W2[f0:f0+FCHUNK]  (wave owns 128 d-cols) ----
    const bf16_t* w2p = W2 + (size_t)(wave * 128 + l16) * D_FF + f0 + quad * 8;
#pragma unroll 2
    for (int k0 = 0; k0 < FCHUNK; k0 += 32) {
      bf16x8_t a0 = *(const bf16x8_t*)(&hs[l16][k0 + quad * 8]);
      bf16x8_t a1 = *(const bf16x8_t*)(&hs[l16 + 16][k0 + quad * 8]);
#pragma unroll
      for (int nt = 0; nt < 8; nt++) {
        bf16x8_t bb = *(const bf16x8_t*)(w2p + (size_t)nt * 16 * D_FF + k0);
        yacc[0][nt] = mfma_bf16(a0, bb, yacc[0][nt]);
        yacc[1][nt] = mfma_bf16(a1, bb, yacc[1][nt]);
      }
    }
  }

  // epilogue: + b2, * gate, scatter
#pragma unroll
  for (int mt = 0; mt < 2; mt++) {
#pragma unroll
    for (int i = 0; i < 4; i++) {
      int row = mt * 16 + quad * 4 + i;
      int sl = rslot[row];
      if (sl == 3) continue;
      float g = rgate[row];
      size_t tkoff = (size_t)rtok[row] * D_MODEL;
      if (sl == 2) {
        float* dst = out + tkoff;
#pragma unroll
        for (int nt = 0; nt < 8; nt++) {
          int d = wave * 128 + nt * 16 + l16;
          dst[d] = (yacc[mt][nt][i] + B2[d]) * g;
        }
      } else {
        bf16_t* dst = (sl ? s1 : s0) + tkoff;
#pragma unroll
        for (int nt = 0; nt < 8; nt++) {
          int d = wave * 128 + nt * 16 + l16;
          dst[d] = (bf16_t)((yacc[mt][nt][i] + B2[d]) * g);
        }
      }
    }
  }
}

__global__ void k_combine(const bf16x4_t* __restrict__ s0, const bf16x4_t* __restrict__ s1,
                          float4* __restrict__ out, int n4) {
  int i = blockIdx.x * blockDim.x + threadIdx.x;
  if (i >= n4) return;
  bf16x4_t a = s0[i], b = s1[i];
  float4 o = out[i];
  o.x += (float)a[0] + (float)b[0];
  o.y += (float)a[1] + (float)b[1];
  o.z += (float)a[2] + (float)b[2];
  o.w += (float)a[3] + (float)b[3];
  out[i] = o;
}

extern "C" void kernel_launch(void* const* d_in, const int* in_sizes, int n_in,
                              void* d_out, int out_size, void* d_ws, size_t ws_size,
                              hipStream_t stream) {
  (void)in_sizes; (void)n_in; (void)out_size; (void)ws_size;
  const float* x        = (const float*)d_in[0];
  const int*   task_ids = (const int*)  d_in[1];
  const float* task_emb = (const float*)d_in[2];
  const float* gate_w   = (const float*)d_in[3];
  const float* gate_b   = (const float*)d_in[4];
  const float* w1       = (const float*)d_in[5];
  const float* b1       = (const float*)d_in[6];
  const float* w2       = (const float*)d_in[7];
  const float* b2       = (const float*)d_in[8];
  const float* uw1      = (const float*)d_in[9];
  const float* ub1      = (const float*)d_in[10];
  const float* uw2      = (const float*)d_in[11];
  const float* ub2      = (const float*)d_in[12];

  char* ws = (char*)d_ws;
  bf16_t* xb    = (bf16_t*)(ws + XB_OFF);
  bf16_t* w1t   = (bf16_t*)(ws + W1T_OFF);
  bf16_t* w2t   = (bf16_t*)(ws + W2T_OFF);
  bf16_t* uw1t  = (bf16_t*)(ws + UW1T_OFF);
  bf16_t* uw2t  = (bf16_t*)(ws + UW2T_OFF);
  bf16_t* s0    = (bf16_t*)(ws + S0_OFF);
  bf16_t* s1    = (bf16_t*)(ws + S1_OFF);
  int*    cnts  = (int*)   (ws + CNT_OFF);
  int*    tokl  = (int*)   (ws + TOKL_OFF);
  float*  gatel = (float*) (ws + GATEL_OFF);
  float*  omg   = (float*) (ws + OMEGA_OFF);
  double* tlog  = (double*)(ws + TLOG_OFF);

  float* out    = (float*)d_out;
  float* logits = out + (size_t)TOKENS * D_MODEL;

  hipMemsetAsync(cnts, 0, 64, stream);

  const int n4 = TOKENS * D_MODEL / 4;  // 1048576
  k_convert_x<<<dim3(n4 / 256), 256, 0, stream>>>((const float4*)x, (bf16x4_t*)xb, n4);
  k_transpose<<<dim3(32, 8, NEXP), 256, 0, stream>>>(w1, w1t, D_MODEL, D_FF);   // -> [e][f][d]
  k_transpose<<<dim3(8, 32, NEXP), 256, 0, stream>>>(w2, w2t, D_FF, D_MODEL);   // -> [e][d][f]
  k_transpose<<<dim3(32, 8, 1),    256, 0, stream>>>(uw1, uw1t, D_MODEL, D_FF);
  k_transpose<<<dim3(8, 32, 1),    256, 0, stream>>>(uw2, uw2t, D_FF, D_MODEL);
  k_tlog<<<1, 64, 0, stream>>>(task_ids, task_emb, gate_w, gate_b, tlog);
  k_gate<<<dim3(TOKENS / 4), 256, 0, stream>>>(x, gate_w, tlog, logits, cnts, tokl, gatel, omg);
  k_ffn<<<dim3(TOKENS / MTILE, NEXP + 1), 256, 0, stream>>>(
      xb, w1t, w2t, uw1t, uw2t, b1, b2, ub1, ub2, cnts, tokl, gatel, omg, s0, s1, out);
  k_combine<<<dim3(n4 / 256), 256, 0, stream>>>((const bf16x4_t*)s0, (const bf16x4_t*)s1,
                                                (float4*)out, n4);
}

// Round 2
// 746.531 us; speedup vs baseline: 1.3438x; 1.3438x over previous
//
#include <hip/hip_runtime.h>

#define D_MODEL 512
#define D_FF    2048
#define NEXP    8
#define TOKENS  8192
#define TROWS   25600     // 8192 universal + 16384 expert slots + padding

typedef __bf16 bf16_t;
typedef __attribute__((ext_vector_type(8))) __bf16 bf16x8_t;
typedef __attribute__((ext_vector_type(4))) __bf16 bf16x4_t;
typedef __attribute__((ext_vector_type(4))) float  f32x4_t;

// ---- workspace layout (bytes) ----
#define W1P_OFF    0u            // bf16 [8][16][2048][32]   k-slab pack of w1
#define UW1P_OFF   16777216u     // bf16 [16][2048][32]
#define W2P_OFF    18874368u     // bf16 [8][64][512][32]
#define UW2P_OFF   35651584u     // bf16 [64][512][32]
#define S0_OFF     37748736u     // bf16 [8192][512]
#define S1_OFF     46137344u     // bf16 [8192][512]
#define CNT_OFF    54525952u     // int[16]
#define TOKL_OFF   54526016u     // int  [8][8192]  entry=(token<<1)|slot
#define GATEL_OFF  54788160u     // float[8][8192]
#define OMEGA_OFF  55050304u     // float[8192]
#define TLOG_OFF   55083072u     // double[8][8]
#define SOFF_OFF   55083584u     // int[16] section row offsets
#define SPC_OFF    55083648u     // int[16] section padded counts
#define RMETA_OFF  55083712u     // int[25600]  (tok<<2)|slot; slot 0/1 expert,2 univ,3 pad
#define RGATE_OFF  55186112u     // float[25600]
#define XGP_OFF    55288512u     // bf16 [16][25600][32]  k-slab gathered X
#define HP_OFF     81502912u     // bf16 [64][25600][32]  k-slab h
// end ≈ 186.4 MB

__device__ inline f32x4_t mfma_bf16(bf16x8_t a, bf16x8_t b, f32x4_t c) {
  return __builtin_amdgcn_mfma_f32_16x16x32_bf16(a, b, c, 0, 0, 0);
}

__device__ __forceinline__ void load_lds16(const void* g, void* l) {
  __builtin_amdgcn_global_load_lds(
      (const __attribute__((address_space(1))) unsigned int*)g,
      (__attribute__((address_space(3))) unsigned int*)l, 16, 0, 0);
}

// pack in[R][C] f32 -> out[R/32][C][32] bf16   (out[s][c][j] = in[s*32+j][c])
__global__ void k_pack(const float* __restrict__ in, bf16_t* __restrict__ out, int R, int C) {
  __shared__ float tile[64][65];
  const size_t mat = (size_t)blockIdx.z * R * C;
  in  += mat;
  out += mat;
  int r0 = blockIdx.y * 64, c0 = blockIdx.x * 64;
  for (int i = threadIdx.x; i < 4096; i += 256) {
    int r = i >> 6, c = i & 63;
    tile[r][c] = in[(size_t)(r0 + r) * C + c0 + c];
  }
  __syncthreads();
  int item = threadIdx.x >> 1, jh = threadIdx.x & 1;
  int c = item & 63, s = item >> 6;
  union { bf16_t h[16]; uint4 u[2]; } t;
#pragma unroll
  for (int k = 0; k < 16; k++) t.h[k] = (bf16_t)tile[s * 32 + jh * 16 + k][c];
  char* dst = (char*)out + ((size_t)((r0 >> 5) + s) * C + (c0 + c)) * 64 + jh * 32;
  ((uint4*)dst)[0] = t.u[0];
  ((uint4*)dst)[1] = t.u[1];
}

__global__ void k_tlog(const int* __restrict__ task_ids, const float* __restrict__ task_emb,
                       const float* __restrict__ gate_w, const float* __restrict__ gate_b,
                       double* __restrict__ tlog) {
  int i = threadIdx.x;
  if (i >= 64) return;
  int b = i >> 3, e = i & 7;
  const float* te = task_emb + (size_t)task_ids[b] * D_MODEL;
  double acc = (double)gate_b[e];
  for (int d = 0; d < D_MODEL; d++)
    acc += (double)te[d] * (double)gate_w[(size_t)(D_MODEL + d) * NEXP + e];
  tlog[i] = acc;
}

__global__ void k_gate(const float* __restrict__ x, const float* __restrict__ gate_w,
                       const double* __restrict__ tlog,
                       float* __restrict__ logits_out,
                       int* __restrict__ counts, int* __restrict__ tokl,
                       float* __restrict__ gatel, float* __restrict__ omega) {
  int gtid = blockIdx.x * blockDim.x + threadIdx.x;
  int t = gtid >> 6;
  int lane = gtid & 63;
  if (t >= TOKENS) return;
  const float* xr = x + (size_t)t * D_MODEL;
  int d0 = lane * 8;
  float4 xa = *(const float4*)(xr + d0);
  float4 xc = *(const float4*)(xr + d0 + 4);
  float xv[8] = {xa.x, xa.y, xa.z, xa.w, xc.x, xc.y, xc.z, xc.w};
  double acc[NEXP];
#pragma unroll
  for (int e = 0; e < NEXP; e++) acc[e] = 0.0;
#pragma unroll
  for (int j = 0; j < 8; j++) {
    const float* gwr = gate_w + (size_t)(d0 + j) * NEXP;
    float4 g0 = *(const float4*)gwr;
    float4 g1 = *(const float4*)(gwr + 4);
    double xd = (double)xv[j];
    acc[0] += xd * (double)g0.x; acc[1] += xd * (double)g0.y;
    acc[2] += xd * (double)g0.z; acc[3] += xd * (double)g0.w;
    acc[4] += xd * (double)g1.x; acc[5] += xd * (double)g1.y;
    acc[6] += xd * (double)g1.z; acc[7] += xd * (double)g1.w;
  }
#pragma unroll
  for (int off = 32; off > 0; off >>= 1) {
#pragma unroll
    for (int e = 0; e < NEXP; e++) acc[e] += __shfl_xor(acc[e], off);
  }
  if (lane == 0) {
    int b = t >> 10;
    double lg[NEXP];
#pragma unroll
    for (int e = 0; e < NEXP; e++) {
      lg[e] = acc[e] + tlog[b * NEXP + e];
      logits_out[(size_t)t * NEXP + e] = (float)lg[e];
    }
    int e0 = 0;
    for (int e = 1; e < NEXP; e++) if (lg[e] > lg[e0]) e0 = e;
    int e1 = (e0 == 0) ? 1 : 0;
    for (int e = 0; e < NEXP; e++) if (e != e0 && lg[e] > lg[e1]) e1 = e;
    double p0 = 1.0 / (1.0 + exp(lg[e1] - lg[e0]));
    float g0f = (float)p0;
    float g1f = (float)(1.0 - p0);
    omega[t] = 1.0f - g0f;
    int i0 = atomicAdd(counts + e0, 1);
    tokl[e0 * TOKENS + i0]  = (t << 1);
    gatel[e0 * TOKENS + i0] = g0f;
    int i1 = atomicAdd(counts + e1, 1);
    tokl[e1 * TOKENS + i1]  = (t << 1) | 1;
    gatel[e1 * TOKENS + i1] = g1f;
  }
}

// single block: build section offsets + row metadata
__global__ void k_sched(const int* __restrict__ cnts, int* __restrict__ soff, int* __restrict__ spc,
                        const int* __restrict__ tokl, const float* __restrict__ gatel,
                        const float* __restrict__ omega,
                        int* __restrict__ rmeta, float* __restrict__ rgate) {
  __shared__ int sh_off[9], sh_pc[9], sh_cnt[9];
  if (threadIdx.x == 0) {
    sh_off[8] = 0; sh_pc[8] = TOKENS; sh_cnt[8] = TOKENS;
    soff[8] = 0; spc[8] = TOKENS;
    int off = TOKENS;
    for (int e = 0; e < 8; e++) {
      int c = cnts[e];
      int p = (c + 127) & ~127;
      sh_off[e] = off; sh_pc[e] = p; sh_cnt[e] = c;
      soff[e] = off; spc[e] = p;
      off += p;
    }
  }
  __syncthreads();
  for (int r = threadIdx.x; r < TOKENS; r += 256) {
    rmeta[r] = (r << 2) | 2;
    rgate[r] = omega[r];
  }
  for (int e = 0; e < 8; e++) {
    int off = sh_off[e], p = sh_pc[e], c = sh_cnt[e];
    for (int i = threadIdx.x; i < p; i += 256) {
      if (i < c) {
        int en = tokl[e * TOKENS + i];
        rmeta[off + i] = ((en >> 1) << 2) | (en & 1);
        rgate[off + i] = gatel[e * TOKENS + i];
      } else {
        rmeta[off + i] = 3;
        rgate[off + i] = 0.f;
      }
    }
  }
  int tot = sh_off[7] + sh_pc[7];
  for (int r = tot + threadIdx.x; r < TROWS; r += 256) { rmeta[r] = 3; rgate[r] = 0.f; }
}

// gather X rows (f32 -> bf16) into k-slab layout xgp[s][row][32]
__global__ void k_gather(const float* __restrict__ x, const int* __restrict__ rmeta,
                         bf16_t* __restrict__ xgp) {
  int rbase = blockIdx.x * 128;
  for (int it = 0; it < 8; it++) {
    int id = it * 256 + threadIdx.x;
    int row = rbase + (id >> 4), s = id & 15;
    int meta = rmeta[row];
    union { bf16_t h[32]; uint4 u[4]; } t;
    if ((meta & 3) == 3) {
#pragma unroll
      for (int j = 0; j < 4; j++) t.u[j] = uint4{0, 0, 0, 0};
    } else {
      const float* src = x + (size_t)(meta >> 2) * D_MODEL + s * 32;
#pragma unroll
      for (int j = 0; j < 32; j += 4) {
        float4 v = *(const float4*)(src + j);
        t.h[j] = (bf16_t)v.x; t.h[j + 1] = (bf16_t)v.y;
        t.h[j + 2] = (bf16_t)v.z; t.h[j + 3] = (bf16_t)v.w;
      }
    }
    char* dst = (char*)xgp + ((size_t)s * TROWS + row) * 64;
#pragma unroll
    for (int j = 0; j < 4; j++) ((uint4*)dst)[j] = t.u[j];
  }
}

// GEMM1: h[rows][2048] = gelu(Xg @ W1 + b1), k-slab in, k-slab out
__global__ __launch_bounds__(256) void k_gemm1(
    const bf16_t* __restrict__ xgp, const bf16_t* __restrict__ w1p,
    const bf16_t* __restrict__ uw1p,
    const float* __restrict__ b1, const float* __restrict__ ub1,
    const int* __restrict__ soff, const int* __restrict__ spc,
    bf16_t* __restrict__ hp) {
  const int sec = blockIdx.z, mt = blockIdx.x, ft = blockIdx.y;
  if (mt * 128 >= spc[sec]) return;
  const int groff = soff[sec];
  const char* Bbase = (const char*)((sec == 8) ? uw1p : (w1p + (size_t)sec * 16 * D_FF * 32));
  const float* bias = (sec == 8) ? ub1 : (b1 + sec * D_FF);

  __shared__ char smem[128 * 136 * 2];   // 16KB tiles overlay / epilogue buffer
  const int tid = threadIdx.x, wave = tid >> 6, lane = tid & 63;
  const int l16 = lane & 15, quad = lane >> 4;
  const int wm = wave & 1, wn = wave >> 1;

  f32x4_t acc[4][4];
#pragma unroll
  for (int i = 0; i < 4; i++)
#pragma unroll
    for (int j = 0; j < 4; j++) acc[i][j] = f32x4_t{0.f, 0.f, 0.f, 0.f};

  const char* Ab = (const char*)xgp + ((size_t)(groff + mt * 128)) * 64 + lane * 16;
  const char* Bb = Bbase + ((size_t)ft * 128) * 64 + lane * 16;

  for (int s = 0; s < 16; s++) {
    const char* Ag = Ab + (size_t)s * (TROWS * 64);
    const char* Bg = Bb + (size_t)s * (D_FF * 64);
#pragma unroll
    for (int i = 0; i < 4; i++) {
      int c = wave * 4 + i;
      if (c < 8) load_lds16(Ag + c * 1024, smem + c * 1024);
      else       load_lds16(Bg + (c - 8) * 1024, smem + 8192 + (c - 8) * 1024);
    }
    __syncthreads();
    bf16x8_t af[4], bfr[4];
#pragma unroll
    for (int f = 0; f < 4; f++)
      af[f] = *(const bf16x8_t*)(smem + ((wm * 64 + f * 16 + l16) * 64) + quad * 16);
#pragma unroll
    for (int f = 0; f < 4; f++)
      bfr[f] = *(const bf16x8_t*)(smem + 8192 + ((wn * 64 + f * 16 + l16) * 64) + quad * 16);
#pragma unroll
    for (int fm = 0; fm < 4; fm++)
#pragma unroll
      for (int fn = 0; fn < 4; fn++)
        acc[fm][fn] = mfma_bf16(af[fm], bfr[fn], acc[fm][fn]);
    __syncthreads();
  }

  // epilogue: bias + exact gelu -> LDS [128][136] bf16 -> hp k-slab
  bf16_t* ep = (bf16_t*)smem;
#pragma unroll
  for (int fm = 0; fm < 4; fm++)
#pragma unroll
    for (int fn = 0; fn < 4; fn++)
#pragma unroll
      for (int i = 0; i < 4; i++) {
        int row = wm * 64 + fm * 16 + quad * 4 + i;
        int col = wn * 64 + fn * 16 + l16;
        float v = acc[fm][fn][i] + bias[ft * 128 + col];
        float gv = 0.5f * v * (1.0f + erff(v * 0.70710678118654752f));
        ep[row * 136 + col] = (bf16_t)gv;
      }
  __syncthreads();
#pragma unroll
  for (int i = 0; i < 2; i++) {
    int id = i * 256 + tid;
    int row = id & 127, cc = id >> 7;
    const uint4* src = (const uint4*)(ep + row * 136 + cc * 32);
    char* dst = (char*)hp + ((size_t)(ft * 4 + cc) * TROWS + groff + mt * 128 + row) * 64;
#pragma unroll
    for (int j = 0; j < 4; j++) ((uint4*)dst)[j] = src[j];
  }
}

// GEMM2: y[rows][512] = h @ W2 + b2, gate-scale, scatter to s0/s1/out
__global__ __launch_bounds__(256) void k_gemm2(
    const bf16_t* __restrict__ hp, const bf16_t* __restrict__ w2p,
    const bf16_t* __restrict__ uw2p,
    const float* __restrict__ b2, const float* __restrict__ ub2,
    const int* __restrict__ soff, const int* __restrict__ spc,
    const int* __restrict__ rmeta, const float* __restrict__ rgate,
    bf16_t* __restrict__ s0, bf16_t* __restrict__ s1, float* __restrict__ out) {
  const int sec = blockIdx.z, mt = blockIdx.x, nt = blockIdx.y;
  if (mt * 128 >= spc[sec]) return;
  const int groff = soff[sec];
  const char* Bbase = (const char*)((sec == 8) ? uw2p : (w2p + (size_t)sec * 64 * D_MODEL * 32));
  const float* bias = (sec == 8) ? ub2 : (b2 + sec * D_MODEL);

  __shared__ char smem[16384];
  const int tid = threadIdx.x, wave = tid >> 6, lane = tid & 63;
  const int l16 = lane & 15, quad = lane >> 4;
  const int wm = wave & 1, wn = wave >> 1;

  f32x4_t acc[4][4];
#pragma unroll
  for (int i = 0; i < 4; i++)
#pragma unroll
    for (int j = 0; j < 4; j++) acc[i][j] = f32x4_t{0.f, 0.f, 0.f, 0.f};

  const char* Ab = (const char*)hp + ((size_t)(groff + mt * 128)) * 64 + lane * 16;
  const char* Bb = Bbase + ((size_t)nt * 128) * 64 + lane * 16;

  for (int s = 0; s < 64; s++) {
    const char* Ag = Ab + (size_t)s * (TROWS * 64);
    const char* Bg = Bb + (size_t)s * (D_MODEL * 64);
#pragma unroll
    for (int i = 0; i < 4; i++) {
      int c = wave * 4 + i;
      if (c < 8) load_lds16(Ag + c * 1024, smem + c * 1024);
      else       load_lds16(Bg + (c - 8) * 1024, smem + 8192 + (c - 8) * 1024);
    }
    __syncthreads();
    bf16x8_t af[4], bfr[4];
#pragma unroll
    for (int f = 0; f < 4; f++)
      af[f] = *(const bf16x8_t*)(smem + ((wm * 64 + f * 16 + l16) * 64) + quad * 16);
#pragma unroll
    for (int f = 0; f < 4; f++)
      bfr[f] = *(const bf16x8_t*)(smem + 8192 + ((wn * 64 + f * 16 + l16) * 64) + quad * 16);
#pragma unroll
    for (int fm = 0; fm < 4; fm++)
#pragma unroll
      for (int fn = 0; fn < 4; fn++)
        acc[fm][fn] = mfma_bf16(af[fm], bfr[fn], acc[fm][fn]);
    __syncthreads();
  }

  // epilogue: +b2, *gate, scatter by slot
#pragma unroll
  for (int fm = 0; fm < 4; fm++) {
#pragma unroll
    for (int i = 0; i < 4; i++) {
      int grow = groff + mt * 128 + wm * 64 + fm * 16 + quad * 4 + i;
      int meta = rmeta[grow];
      int slot = meta & 3;
      if (slot == 3) continue;
      float g = rgate[grow];
      size_t tkoff = (size_t)(meta >> 2) * D_MODEL;
      if (slot == 2) {
        float* dst = out + tkoff;
#pragma unroll
        for (int fn = 0; fn < 4; fn++) {
          int d = nt * 128 + wn * 64 + fn * 16 + l16;
          dst[d] = (acc[fm][fn][i] + bias[d]) * g;
        }
      } else {
        bf16_t* dst = (slot ? s1 : s0) + tkoff;
#pragma unroll
        for (int fn = 0; fn < 4; fn++) {
          int d = nt * 128 + wn * 64 + fn * 16 + l16;
          dst[d] = (bf16_t)((acc[fm][fn][i] + bias[d]) * g);
        }
      }
    }
  }
}

__global__ void k_combine(const bf16x4_t* __restrict__ s0, const bf16x4_t* __restrict__ s1,
                          float4* __restrict__ out, int n4) {
  int i = blockIdx.x * blockDim.x + threadIdx.x;
  if (i >= n4) return;
  bf16x4_t a = s0[i], b = s1[i];
  float4 o = out[i];
  o.x += (float)a[0] + (float)b[0];
  o.y += (float)a[1] + (float)b[1];
  o.z += (float)a[2] + (float)b[2];
  o.w += (float)a[3] + (float)b[3];
  out[i] = o;
}

extern "C" void kernel_launch(void* const* d_in, const int* in_sizes, int n_in,
                              void* d_out, int out_size, void* d_ws, size_t ws_size,
                              hipStream_t stream) {
  (void)in_sizes; (void)n_in; (void)out_size; (void)ws_size;
  const float* x        = (const float*)d_in[0];
  const int*   task_ids = (const int*)  d_in[1];
  const float* task_emb = (const float*)d_in[2];
  const float* gate_w   = (const float*)d_in[3];
  const float* gate_b   = (const float*)d_in[4];
  const float* w1       = (const float*)d_in[5];
  const float* b1       = (const float*)d_in[6];
  const float* w2       = (const float*)d_in[7];
  const float* b2       = (const float*)d_in[8];
  const float* uw1      = (const float*)d_in[9];
  const float* ub1      = (const float*)d_in[10];
  const float* uw2      = (const float*)d_in[11];
  const float* ub2      = (const float*)d_in[12];

  char* ws = (char*)d_ws;
  bf16_t* w1p   = (bf16_t*)(ws + W1P_OFF);
  bf16_t* uw1p  = (bf16_t*)(ws + UW1P_OFF);
  bf16_t* w2p   = (bf16_t*)(ws + W2P_OFF);
  bf16_t* uw2p  = (bf16_t*)(ws + UW2P_OFF);
  bf16_t* s0    = (bf16_t*)(ws + S0_OFF);
  bf16_t* s1    = (bf16_t*)(ws + S1_OFF);
  int*    cnts  = (int*)   (ws + CNT_OFF);
  int*    tokl  = (int*)   (ws + TOKL_OFF);
  float*  gatel = (float*) (ws + GATEL_OFF);
  float*  omg   = (float*) (ws + OMEGA_OFF);
  double* tlog  = (double*)(ws + TLOG_OFF);
  int*    soff  = (int*)   (ws + SOFF_OFF);
  int*    spc   = (int*)   (ws + SPC_OFF);
  int*    rmeta = (int*)   (ws + RMETA_OFF);
  float*  rgate = (float*) (ws + RGATE_OFF);
  bf16_t* xgp   = (bf16_t*)(ws + XGP_OFF);
  bf16_t* hp    = (bf16_t*)(ws + HP_OFF);

  float* out    = (float*)d_out;
  float* logits = out + (size_t)TOKENS * D_MODEL;

  hipMemsetAsync(cnts, 0, 64, stream);

  k_pack<<<dim3(32, 8, NEXP), 256, 0, stream>>>(w1, w1p, D_MODEL, D_FF);
  k_pack<<<dim3(8, 32, NEXP), 256, 0, stream>>>(w2, w2p, D_FF, D_MODEL);
  k_pack<<<dim3(32, 8, 1),    256, 0, stream>>>(uw1, uw1p, D_MODEL, D_FF);
  k_pack<<<dim3(8, 32, 1),    256, 0, stream>>>(uw2, uw2p, D_FF, D_MODEL);
  k_tlog<<<1, 64, 0, stream>>>(task_ids, task_emb, gate_w, gate_b, tlog);
  k_gate<<<dim3(TOKENS / 4), 256, 0, stream>>>(x, gate_w, tlog, logits, cnts, tokl, gatel, omg);
  k_sched<<<1, 256, 0, stream>>>(cnts, soff, spc, tokl, gatel, omg, rmeta, rgate);
  k_gather<<<dim3(TROWS / 128), 256, 0, stream>>>(x, rmeta, xgp);
  k_gemm1<<<dim3(64, 16, 9), 256, 0, stream>>>(xgp, w1p, uw1p, b1, ub1, soff, spc, hp);
  k_gemm2<<<dim3(64, 4, 9), 256, 0, stream>>>(hp, w2p, uw2p, b2, ub2, soff, spc,
                                              rmeta, rgate, s0, s1, out);
  const int n4 = TOKENS * D_MODEL / 4;
  k_combine<<<dim3(n4 / 256), 256, 0, stream>>>((const bf16x4_t*)s0, (const bf16x4_t*)s1,
                                                (float4*)out, n4);
}